// Round 6
// baseline (283.697 us; speedup 1.0000x reference)
//
#include <hip/hip_runtime.h>
#include <math.h>

#define W 480
#define HT 480
#define HW (W*HT)
#define GE 900          // 230400/256
#define PP 225
#define NPATCH 1024
#define EQCAP 8192

struct State {
  unsigned histA[3][256];   // radix levels 0..2 (dark-channel top-k, descending)
  unsigned slotP[3], slotK[3];
  unsigned tickets[8];
  float sumA[3];
  unsigned eqCount;
  float A[3];
  unsigned tminbits;
  unsigned eqIdx[EQCAP];    // packed (low8<<24)|idx for 24-bit-prefix matches
  float tp1[NPATCH];
  float tp2[NPATCH];
};

// ---------- device-scope helpers ----------
__device__ __forceinline__ unsigned aload(const unsigned* p) {
  return __hip_atomic_load(p, __ATOMIC_RELAXED, __HIP_MEMORY_SCOPE_AGENT);
}

// returns true for exactly one block, after all blocks' prior work is globally visible
__device__ __forceinline__ bool last_block(unsigned* ticket, unsigned nb) {
  __shared__ unsigned isl;
  __syncthreads();
  if (threadIdx.x == 0) {
    __threadfence();
    unsigned tk = __hip_atomic_fetch_add(ticket, 1u, __ATOMIC_ACQ_REL, __HIP_MEMORY_SCOPE_AGENT);
    isl = (tk == nb - 1u) ? 1u : 0u;
  }
  __syncthreads();
  return isl != 0u;
}

// ---------- cooperative radix-select resolve (256 threads; h global if glob) ----------
__device__ __forceinline__ void resolve_level(const unsigned* __restrict__ h,
                                              unsigned k_in, int desc, int glob,
                                              unsigned* lds,
                                              unsigned& chosen, unsigned& k_out) {
  int t = threadIdx.x;
  int idx = desc ? (255 - t) : t;
  unsigned c = glob ? aload(&h[idx]) : h[idx];
  lds[t] = c;
  __syncthreads();
  for (int s = 1; s < 256; s <<= 1) {           // Hillis-Steele inclusive scan
    unsigned add = (t >= s) ? lds[t - s] : 0u;
    __syncthreads();
    lds[t] += add;
    __syncthreads();
  }
  unsigned incl = lds[t];
  unsigned excl = incl - c;
  if (incl >= k_in && excl < k_in) { lds[256] = (unsigned)t; lds[257] = k_in - excl; }
  __syncthreads();
  unsigned tt = lds[256];
  k_out = lds[257];
  chosen = desc ? (255u - tt) : tt;
  __syncthreads();
}

// ---------- 1: init state + channel-min + horizontal 55-min (one row per block) ----------
__global__ __launch_bounds__(512) void k_rowmin(const float* __restrict__ img,
                                                float* __restrict__ rowmin, State* st) {
  __shared__ float l[534];
  int y = blockIdx.x, t = threadIdx.x;
  for (int i = t; i < 534; i += 512) {
    int col = i - 27;
    float v = 1.0f;                              // pad (constant_values=1.0)
    if ((unsigned)col < (unsigned)W) {
      int q = y * W + col;
      v = fminf(fminf(img[q], img[HW + q]), img[2 * HW + q]);
    }
    l[i] = v;
  }
  if (y == 0 && t < 256) {
    for (int i = 0; i < 3; ++i) st->histA[i][t] = 0u;
    if (t < 8) st->tickets[t] = 0u;
    if (t == 0) { st->sumA[0] = 0.f; st->sumA[1] = 0.f; st->sumA[2] = 0.f; st->eqCount = 0u; }
  }
  __syncthreads();
  if (t < W) {
    float m = l[t];
    for (int d = 1; d < 55; ++d) m = fminf(m, l[t + d]);
    rowmin[y * W + t] = m;
  }
}

// ---------- 2: vertical 8-row chunk mins (60 chunks x 480 cols) ----------
__global__ __launch_bounds__(256) void k_vchunk(const float* __restrict__ rowmin,
                                                float* __restrict__ cmin) {
  int p = blockIdx.x * 256 + threadIdx.x;
  if (p >= 60 * W) return;
  int c = p / W, x = p - c * W;
  float m = INFINITY;
  for (int r = 0; r < 8; ++r) m = fminf(m, rowmin[(c * 8 + r) * W + x]);
  cmin[p] = m;
}

// ---------- 3: vertical 55-min; fused hist level-0; last block resolves L0 ----------
__global__ __launch_bounds__(256) void k_minV2(const float* __restrict__ rowmin,
                                               const float* __restrict__ cmin,
                                               float* __restrict__ dc, State* st) {
  __shared__ unsigned lh[256];
  __shared__ unsigned lds[258];
  int t = threadIdx.x;
  lh[t] = 0u;
  __syncthreads();
  int p = blockIdx.x * 256 + t;
  int y = p / W, x = p - y * W;
  int lo = y - 27, hi = y + 27;
  float m = (lo < 0 || hi >= HT) ? 1.0f : INFINITY;
  int lo2 = max(lo, 0), hi2 = min(hi, HT - 1);
  int cs = (lo2 + 7) >> 3, ce = ((hi2 + 1) >> 3) - 1;
  for (int c = cs; c <= ce; ++c) m = fminf(m, cmin[c * W + x]);
  for (int yy = lo2; yy < (cs << 3); ++yy) m = fminf(m, rowmin[yy * W + x]);
  for (int yy = (ce + 1) << 3; yy <= hi2; ++yy) m = fminf(m, rowmin[yy * W + x]);
  dc[p] = m;
  atomicAdd(&lh[__float_as_uint(m) >> 24], 1u);
  __syncthreads();
  unsigned c = lh[t];
  if (c) atomicAdd(&st->histA[0][t], c);
  if (last_block(&st->tickets[0], GE)) {
    unsigned ch, kn;
    resolve_level(st->histA[0], 230u, 1, 1, lds, ch, kn);
    if (t == 0) { st->slotP[0] = ch << 24; st->slotK[0] = kn; }
  }
}

// ---------- 4,5: radix hist pass for level 1,2; last block resolves its level ----------
__global__ __launch_bounds__(256) void k_histL(const float* __restrict__ dc,
                                               State* st, int level) {
  __shared__ unsigned lh[256];
  __shared__ unsigned lds[258];
  int t = threadIdx.x;
  unsigned prefix = st->slotP[level - 1];
  unsigned k = st->slotK[level - 1];
  lh[t] = 0u;
  __syncthreads();
  int p = blockIdx.x * 256 + t;
  unsigned bits = __float_as_uint(dc[p]);
  unsigned mask = 0xFFFFFFFFu << (32 - 8 * level);
  if ((bits & mask) == prefix)
    atomicAdd(&lh[(bits >> (24 - 8 * level)) & 0xFFu], 1u);
  __syncthreads();
  unsigned c = lh[t];
  if (c) atomicAdd(&st->histA[level][t], c);
  if (last_block(&st->tickets[level], GE)) {
    unsigned ch, kn;
    resolve_level(st->histA[level], k, 1, 1, lds, ch, kn);
    if (t == 0) { st->slotP[level] = prefix | (ch << (24 - 8 * level)); st->slotK[level] = kn; }
  }
}

// ---------- 6: gather on 24-bit prefix; last block: resolve low byte + tie-break + A ----------
__global__ __launch_bounds__(256) void k_gather24(const float* __restrict__ dc,
                                                  const float* __restrict__ img, State* st) {
  __shared__ unsigned sPk[EQCAP];
  __shared__ unsigned lh[256];
  __shared__ unsigned lds[258];
  __shared__ float ssum[3];
  int t = threadIdx.x;
  unsigned pfx24 = st->slotP[2];     // top-24 prefix, low byte 0
  unsigned k24 = st->slotK[2];
  int p = blockIdx.x * 256 + t;
  unsigned bits = __float_as_uint(dc[p]);
  unsigned top24 = bits & 0xFFFFFF00u;
  if (top24 > pfx24) {
    atomicAdd(&st->sumA[0], img[p]);
    atomicAdd(&st->sumA[1], img[HW + p]);
    atomicAdd(&st->sumA[2], img[2 * HW + p]);
  } else if (top24 == pfx24) {
    unsigned pos = atomicAdd(&st->eqCount, 1u);
    if (pos < (unsigned)EQCAP) st->eqIdx[pos] = ((bits & 0xFFu) << 24) | (unsigned)p;
  }
  if (last_block(&st->tickets[3], GE)) {
    unsigned ne = st->eqCount; if (ne > (unsigned)EQCAP) ne = EQCAP;
    for (int i = t; i < (int)ne; i += 256) sPk[i] = st->eqIdx[i];
    if (t < 3) ssum[t] = 0.f;
    lh[t] = 0u;
    __syncthreads();
    for (int i = t; i < (int)ne; i += 256) atomicAdd(&lh[sPk[i] >> 24], 1u);
    __syncthreads();
    unsigned lb, keq;
    resolve_level(lh, k24, 1, 0, lds, lb, keq);   // low byte of threshold; keq ties needed
    float a0 = 0.f, a1 = 0.f, a2 = 0.f;
    for (int i = t; i < (int)ne; i += 256) {
      unsigned v = sPk[i];
      if ((v >> 24) > lb) {
        unsigned q = v & 0x3FFFFu;
        a0 += img[q]; a1 += img[HW + q]; a2 += img[2 * HW + q];
      }
    }
    // lax.top_k tie-break = lower index first: keq smallest idx among low==lb
    unsigned pfi = 0u, kk = keq;
    for (int lev = 0; lev < 3; ++lev) {
      int s = 16 - 8 * lev;
      __syncthreads();
      lh[t] = 0u;
      __syncthreads();
      for (int i = t; i < (int)ne; i += 256) {
        unsigned v = sPk[i];
        if ((v >> 24) == lb) {
          unsigned idx = v & 0x3FFFFu;
          if ((idx >> (s + 8)) == (pfi >> (s + 8)))
            atomicAdd(&lh[(idx >> s) & 0xFFu], 1u);
        }
      }
      __syncthreads();
      unsigned ch, kn;
      resolve_level(lh, kk, 0, 0, lds, ch, kn);
      pfi |= ch << s;
      kk = kn;
    }
    for (int i = t; i < (int)ne; i += 256) {
      unsigned v = sPk[i];
      if ((v >> 24) == lb) {
        unsigned q = v & 0x3FFFFu;
        if (q <= pfi) { a0 += img[q]; a1 += img[HW + q]; a2 += img[2 * HW + q]; }
      }
    }
    atomicAdd(&ssum[0], a0); atomicAdd(&ssum[1], a1); atomicAdd(&ssum[2], a2);
    __syncthreads();
    if (t == 0) {
      st->A[0] = (st->sumA[0] + ssum[0]) / 230.0f;
      st->A[1] = (st->sumA[1] + ssum[1]) / 230.0f;
      st->A[2] = (st->sumA[2] + ssum[2]) / 230.0f;
    }
  }
}

// ---------- 7: row kernel: SV, I, To(LDS) + fused bccr 15-tap H-maxpool ----------
__global__ __launch_bounds__(512) void k_elem_row(const float* __restrict__ img,
                                                  const State* __restrict__ st,
                                                  float2* __restrict__ SV,
                                                  float* __restrict__ Io,
                                                  float* __restrict__ mh) {
  __shared__ float Tl[494];
  int y = blockIdx.x, t = threadIdx.x;
  if (t < 7) Tl[t] = 0.0f;                        // pad 0 (reference pads t with 0)
  if (t >= 480 && t < 487) Tl[t + 7] = 0.0f;
  if (t < W) {
    int p = y * W + t;
    float A0 = st->A[0], A1 = st->A[1], A2 = st->A[2];
    float r = img[p], g = img[HW + p], bl = img[2 * HW + p];
    float nr = r / A0, ng = g / A1, nb = bl / A2;
    float mx = fmaxf(fmaxf(nr, ng), nb);
    float mn = fminf(fminf(nr, ng), nb);
    float d = mx + 1e-8f;
    SV[p] = make_float2(1.0f / d, 1.0f - mn / d);  // x = X (V1), y = Y (S)
    Io[p] = ((r + g) + bl) / 3.0f;
    const float c20 = (float)(20.0 / 255.0);
    const float c300 = (float)(300.0 / 255.0);
    float t0 = fmaxf((A0 - r) / (A0 - c20), (A0 - r) / (A0 - c300));
    float t1 = fmaxf((A1 - g) / (A1 - c20), (A1 - g) / (A1 - c300));
    float t2 = fmaxf((A2 - bl) / (A2 - c20), (A2 - bl) / (A2 - c300));
    Tl[7 + t] = fmaxf(fmaxf(t0, t1), t2);
  }
  __syncthreads();
  if (t < W) {
    float m = Tl[t];
    for (int d = 1; d < 15; ++d) m = fmaxf(m, Tl[t + d]);
    mh[y * W + t] = m;
  }
}

// ---------- wave reductions ----------
__device__ __forceinline__ float wred_sum(float v) { for (int m = 32; m; m >>= 1) v += __shfl_xor(v, m, 64); return v; }
__device__ __forceinline__ float wred_max(float v) { for (int m = 32; m; m >>= 1) v = fmaxf(v, __shfl_xor(v, m, 64)); return v; }
__device__ __forceinline__ float wred_min(float v) { for (int m = 32; m; m >>= 1) v = fminf(v, __shfl_xor(v, m, 64)); return v; }

// ---------- 8: both patch grids (sign/magnitude slope test) ----------
__global__ __launch_bounds__(256) void k_mega1(const float2* __restrict__ SV, State* st) {
  __shared__ float2 XY[PP];
  __shared__ float part[4][8];
  int b = blockIdx.x;
  int t = threadIdx.x;
  int mode = b >> 10;              // 0: t1 grid, 1: shifted t2 grid
  int pid = b & 1023;
  int ph = pid >> 5, pw = pid & 31;
  if (t < PP) {
    int r = t / 15, c = t - (t / 15) * 15;
    int y, x;
    if (mode == 0) { y = ph * 15 + r; x = pw * 15 + c; }
    else {
      y = ph * 15 + r + 4; y = (y < 7) ? 7 : ((y > 479) ? 479 : y);
      x = pw * 15 + c + 4; x = (x < 7) ? 7 : ((x > 479) ? 479 : x);
    }
    XY[t] = SV[y * W + x];
  }
  __syncthreads();
  float xi = 0.f, yi = 0.f;
  int cnt = 0;
  if (t < PP) {
    xi = XY[t].x; yi = XY[t].y;
    // slope = dY/(dX+1e-8) in (-1,0)  <=>  dY*D < 0  AND  |dY| < |D|
    for (int j = 0; j < PP; ++j) {
      float2 o = XY[j];
      float dY = yi - o.y;
      float D = (xi - o.x) + 1e-8f;
      cnt += ((dY * D < 0.0f) && (fabsf(dY) < fabsf(D))) ? 1 : 0;
    }
  }
  float pmf = (t < PP && cnt >= 113) ? 1.0f : 0.0f;   // scount >= 112.5
  float xm = xi * pmf, ym = yi * pmf;
  float v0 = wred_sum(pmf);
  float v1 = wred_sum(xm);
  float v2 = wred_sum(ym);
  float v3 = wred_sum(xm * ym);
  float v4 = wred_sum(xm * xm);
  float v5 = wred_max((t < PP) ? xm : -INFINITY);
  float v6 = wred_min((t < PP) ? (xi + 1e8f * (1.0f - pmf)) : INFINITY);
  int wid = t >> 6, lane = t & 63;
  if (lane == 0) {
    part[wid][0] = v0; part[wid][1] = v1; part[wid][2] = v2; part[wid][3] = v3;
    part[wid][4] = v4; part[wid][5] = v5; part[wid][6] = v6;
  }
  __syncthreads();
  if (t == 0) {
    float pcount = 0.f, sx = 0.f, sy = 0.f, sxy = 0.f, sxx = 0.f;
    float mxX = -INFINITY, mnX = INFINITY;
    for (int w2 = 0; w2 < 4; ++w2) {
      pcount += part[w2][0]; sx += part[w2][1]; sy += part[w2][2];
      sxy += part[w2][3]; sxx += part[w2][4];
      mxX = fmaxf(mxX, part[w2][5]); mnX = fminf(mnX, part[w2][6]);
    }
    float den = pcount + 1e-5f;
    float mxv = sx / den, myv = sy / den;
    float kk = (sxy - pcount * mxv * myv) / (sxx - pcount * (mxv * mxv) + 1e-5f);
    float bb = myv - kk * mxv;
    float tt = 1.0f + kk / (bb + 1e-8f);
    float len = sqrtf(1.0f + kk * kk) * (mxX - mnX);
    bool m = (pcount > 10.0f) && (len > 0.1f) && (kk > -1.0f) && (kk < 0.0f)
             && (tt > 0.01f) && (tt < 0.99f);
    float res = tt * (m ? 1.0f : 0.0f);   // keep JAX NaN*0 semantics
    if (mode == 0) st->tp1[pid] = res; else st->tp2[pid] = res;
  }
}

// ---------- 9: 2-row bccr V-maxpool+clip (blocks 0..449) | analytic percentile (450) ----------
__global__ __launch_bounds__(256) void k_maxV_pct(const float* __restrict__ mh,
                                                  float* __restrict__ tb, State* st) {
  __shared__ unsigned lh[256];
  __shared__ unsigned lds[258];
  __shared__ float tp1s[NPATCH], tp2s[NPATCH];
  int b = blockIdx.x;
  int t = threadIdx.x;
  if (b < 450) {
    int p = b * 256 + t;          // [0, HW/2)
    int x = p % W, yp = p / W;
    int y0 = 2 * yp;
    float m0 = -INFINITY, m1 = -INFINITY;
    for (int d = 0; d < 16; ++d) {
      int yy = y0 - 7 + d;
      float v = ((unsigned)yy < (unsigned)HT) ? mh[yy * W + x] : 0.0f;
      if (d < 15) m0 = fmaxf(m0, v);
      if (d > 0)  m1 = fmaxf(m1, v);
    }
    tb[y0 * W + x]       = fminf(fmaxf(m0, 0.05f), 1.0f);
    tb[(y0 + 1) * W + x] = fminf(fmaxf(m1, 0.05f), 1.0f);
    return;
  }
  // percentile: t_slp piecewise constant over <=4096 (value, area) regions
  for (int i = t; i < NPATCH; i += 256) { tp1s[i] = st->tp1[i]; tp2s[i] = st->tp2[i]; }
  __syncthreads();
  unsigned prefix = 0u, k = 11521u;   // 1-based rank of sorted[11520]
  for (int level = 0; level < 4; ++level) {
    lh[t] = 0u;
    __syncthreads();
    unsigned mask = (level == 0) ? 0u : (0xFFFFFFFFu << (32 - 8 * level));
    int shift = 24 - 8 * level;
    for (int i = t; i < NPATCH; i += 256) {
      int ph = i >> 5, pw = i & 31;
      float a = tp1s[i];
      int rcnt[2], ridx[2], ccnt[2], cidx[2];
      if (ph == 0) { rcnt[0] = 7; ridx[0] = -1; rcnt[1] = 8; ridx[1] = 0; }
      else         { rcnt[0] = 4; ridx[0] = ph - 1; rcnt[1] = 11; ridx[1] = ph; }
      if (pw == 0) { ccnt[0] = 7; cidx[0] = -1; ccnt[1] = 8; cidx[1] = 0; }
      else         { ccnt[0] = 4; cidx[0] = pw - 1; ccnt[1] = 11; cidx[1] = pw; }
      for (int ri = 0; ri < 2; ++ri)
        for (int ci = 0; ci < 2; ++ci) {
          unsigned area = (unsigned)(rcnt[ri] * ccnt[ci]);
          float bb = 0.0f;
          if (ridx[ri] >= 0 && cidx[ci] >= 0) bb = tp2s[ridx[ri] * 32 + cidx[ci]];
          float r;
          if (a != 0.0f && bb != 0.0f) r = (a + bb) / 2.0f;
          else r = (a != 0.0f) ? a : bb;
          float u = (r > 0.0f) ? r : 10.0f;            // where(t>0,t,10); NaN->10
          unsigned bits = __float_as_uint(u);
          if ((bits & mask) == prefix)
            atomicAdd(&lh[(bits >> shift) & 0xFFu], area);
        }
    }
    __syncthreads();
    unsigned ch, kn;
    resolve_level(lh, k, 0, 0, lds, ch, kn);
    prefix |= ch << shift;
    k = kn;
  }
  if (t == 0) st->tminbits = prefix;
}

// ---------- 10: gf pass-1 horizontal (one row/block), fused t_fusion, float4 out ----------
__global__ __launch_bounds__(512) void k_gf1h(const float* __restrict__ I,
                                              const float* __restrict__ tb,
                                              const State* __restrict__ st,
                                              float4* __restrict__ box4) {
  __shared__ float tp1s[NPATCH], tp2s[NPATCH];
  __shared__ float Pl[540], Il[540];
  int y = blockIdx.x, t = threadIdx.x;
  for (int i = t; i < NPATCH; i += 512) { tp1s[i] = st->tp1[i]; tp2s[i] = st->tp2[i]; }
  __syncthreads();
  float tmin = __uint_as_float(st->tminbits);
  int c1row = (y / 15) * 32;
  bool c2ok = (y >= 7);
  int c2row = c2ok ? ((y - 4) / 15) * 32 : 0;
  for (int i = t; i < 540; i += 512) {
    int col = i - 30;
    float pv = 0.0f, iv = 0.0f;
    if ((unsigned)col < (unsigned)W) {
      int q = y * W + col;
      float a = tp1s[c1row + col / 15];
      float bb = 0.0f;
      if (c2ok && col >= 7) bb = tp2s[c2row + (col - 4) / 15];
      float r;
      if (a != 0.0f && bb != 0.0f) r = (a + bb) / 2.0f;   // NaN != 0 true, as in JAX
      else r = (a != 0.0f) ? a : bb;
      float v = (r > 0.0f) ? r : tb[q];                   // NaN -> tb
      v = (v < tmin) ? tmin : v;
      v = (v > 1.0f) ? 1.0f : v;
      pv = v; iv = I[q];
    }
    Pl[i] = pv; Il[i] = iv;
  }
  __syncthreads();
  if (t < W) {
    float sI = 0.f, sP = 0.f, sIp = 0.f, sII = 0.f;
    for (int d = 0; d < 61; ++d) {
      float iv = Il[t + d], pv = Pl[t + d];
      sI += iv; sP += pv; sIp += iv * pv; sII += iv * iv;
    }
    box4[y * W + t] = make_float4(sI, sP, sIp, sII);
  }
}

// ---------- 11: gf pass-1 vertical, 2 rows/thread ----------
__global__ __launch_bounds__(256) void k_gf1v(const float4* __restrict__ box4,
                                              float2* __restrict__ ab) {
  int p = blockIdx.x * 256 + threadIdx.x;   // [0, HW/2)
  int x = p % W, yp = p / W;
  int y0 = 2 * yp, y1 = y0 + 1;
  float sI = 0.f, sP = 0.f, sIp = 0.f, sII = 0.f;
  int lo = max(y0 - 30, 0), hi = min(y0 + 30, HT - 1);
  for (int yy = lo; yy <= hi; ++yy) {
    float4 v = box4[yy * W + x];
    sI += v.x; sP += v.y; sIp += v.z; sII += v.w;
  }
  int nx = min(x + 30, W - 1) - max(x - 30, 0) + 1;
  {
    float Nn = (float)((hi - lo + 1) * nx);
    float mI = sI / Nn, mP = sP / Nn, mIp = sIp / Nn, mII = sII / Nn;
    float cov = mIp - mI * mP;
    float var = mII - mI * mI;
    float av = cov / (var + 1e-3f);
    ab[y0 * W + x] = make_float2(av, mP - av * mI);
  }
  {
    int yr = y0 - 30, ya = y0 + 31;
    if (yr >= 0)  { float4 v = box4[yr * W + x]; sI -= v.x; sP -= v.y; sIp -= v.z; sII -= v.w; }
    if (ya < HT)  { float4 v = box4[ya * W + x]; sI += v.x; sP += v.y; sIp += v.z; sII += v.w; }
    int lo1 = max(y1 - 30, 0), hi1 = min(y1 + 30, HT - 1);
    float Nn = (float)((hi1 - lo1 + 1) * nx);
    float mI = sI / Nn, mP = sP / Nn, mIp = sIp / Nn, mII = sII / Nn;
    float cov = mIp - mI * mP;
    float var = mII - mI * mI;
    float av = cov / (var + 1e-3f);
    ab[y1 * W + x] = make_float2(av, mP - av * mI);
  }
}

// ---------- 12: gf pass-2 horizontal (one row/block), float2 in/out ----------
__global__ __launch_bounds__(512) void k_gf2h(const float2* __restrict__ ab,
                                              float2* __restrict__ hab) {
  __shared__ float2 l[540];
  int y = blockIdx.x, t = threadIdx.x;
  for (int i = t; i < 540; i += 512) {
    int col = i - 30;
    float2 v = make_float2(0.f, 0.f);
    if ((unsigned)col < (unsigned)W) v = ab[y * W + col];
    l[i] = v;
  }
  __syncthreads();
  if (t < W) {
    float sa = 0.f, sb = 0.f;
    for (int d = 0; d < 61; ++d) { float2 v = l[t + d]; sa += v.x; sb += v.y; }
    hab[y * W + t] = make_float2(sa, sb);
  }
}

// ---------- 13: gf pass-2 vertical + restore epilogue, 2 rows/thread ----------
__global__ __launch_bounds__(256) void k_gf2vfin(const float2* __restrict__ hab,
                                                 const float* __restrict__ I,
                                                 const float* __restrict__ img,
                                                 const State* __restrict__ st,
                                                 float* __restrict__ out) {
  int p = blockIdx.x * 256 + threadIdx.x;   // [0, HW/2)
  int x = p % W, yp = p / W;
  int y0 = 2 * yp, y1 = y0 + 1;
  float A0 = st->A[0], A1 = st->A[1], A2 = st->A[2];
  float sa = 0.f, sb = 0.f;
  int lo = max(y0 - 30, 0), hi = min(y0 + 30, HT - 1);
  for (int yy = lo; yy <= hi; ++yy) { float2 v = hab[yy * W + x]; sa += v.x; sb += v.y; }
  int nx = min(x + 30, W - 1) - max(x - 30, 0) + 1;
  {
    float Nn = (float)((hi - lo + 1) * nx);
    int q = y0 * W + x;
    float tref = (sa / Nn) * I[q] + (sb / Nn);
    out[q]          = (img[q]          - A0) / tref + A0;
    out[HW + q]     = (img[HW + q]     - A1) / tref + A1;
    out[2 * HW + q] = (img[2 * HW + q] - A2) / tref + A2;
  }
  {
    int yr = y0 - 30, ya = y0 + 31;
    if (yr >= 0) { float2 v = hab[yr * W + x]; sa -= v.x; sb -= v.y; }
    if (ya < HT) { float2 v = hab[ya * W + x]; sa += v.x; sb += v.y; }
    int lo1 = max(y1 - 30, 0), hi1 = min(y1 + 30, HT - 1);
    float Nn = (float)((hi1 - lo1 + 1) * nx);
    int q = y1 * W + x;
    float tref = (sa / Nn) * I[q] + (sb / Nn);
    out[q]          = (img[q]          - A0) / tref + A0;
    out[HW + q]     = (img[HW + q]     - A1) / tref + A1;
    out[2 * HW + q] = (img[2 * HW + q] - A2) / tref + A2;
  }
}

// ---------- launch: 13 dispatches ----------
extern "C" void kernel_launch(void* const* d_in, const int* in_sizes, int n_in,
                              void* d_out, int out_size, void* d_ws, size_t ws_size,
                              hipStream_t stream) {
  (void)in_sizes; (void)n_in; (void)out_size; (void)ws_size;
  const float* img = (const float*)d_in[0];
  float* out = (float*)d_out;
  State* st = (State*)d_ws;
  float* sb = (float*)((char*)d_ws + 65536);
  float* bufA  = sb;                          // dc -> tb
  float* bufRM = sb + HW;                     // rowmin
  float* bufI  = sb + 2 * HW;                 // I
  float2* SV   = (float2*)(sb + 3 * HW);      // [3HW,5HW)
  float* cmin  = sb + 5 * HW;                 // 28800 floats
  float* mh    = sb + 6 * HW;                 // [6HW,7HW)
  float4* box4 = (float4*)(sb + 3 * HW);      // [3HW,7HW)  (SV/cmin/mh dead by then)
  float2* ab   = (float2*)(sb + 7 * HW);      // [7HW,9HW)
  float2* hab  = (float2*)(sb + 3 * HW);      // [3HW,5HW)  (box4 dead by then)

  dim3 b256(256), b512(512);
  dim3 ge(GE), rows(HT), half(450);

  k_rowmin<<<rows, b512, 0, stream>>>(img, bufRM, st);
  k_vchunk<<<dim3(113), b256, 0, stream>>>(bufRM, cmin);
  k_minV2<<<ge, b256, 0, stream>>>(bufRM, cmin, bufA, st);
  k_histL<<<ge, b256, 0, stream>>>(bufA, st, 1);
  k_histL<<<ge, b256, 0, stream>>>(bufA, st, 2);
  k_gather24<<<ge, b256, 0, stream>>>(bufA, img, st);
  k_elem_row<<<rows, b512, 0, stream>>>(img, st, SV, bufI, mh);
  k_mega1<<<dim3(2048), b256, 0, stream>>>(SV, st);
  k_maxV_pct<<<dim3(451), b256, 0, stream>>>(mh, bufA, st);
  k_gf1h<<<rows, b512, 0, stream>>>(bufI, bufA, st, box4);
  k_gf1v<<<half, b256, 0, stream>>>(box4, ab);
  k_gf2h<<<rows, b512, 0, stream>>>(ab, hab);
  k_gf2vfin<<<half, b256, 0, stream>>>(hab, bufI, img, st, out);
}

// Round 7
// 192.719 us; speedup vs baseline: 1.4721x; 1.4721x over previous
//
#include <hip/hip_runtime.h>
#include <math.h>

#define W 480
#define HT 480
#define HW (W*HT)
#define GE 900          // 230400/256
#define PP 225
#define NPATCH 1024
#define EQCAP 8192

struct State {
  unsigned histA[3][256];   // radix levels 0..2 (dark-channel top-k, descending)
  unsigned slotP2, slotK2;  // 24-bit prefix + remaining rank (written by gather24 blk0)
  float sumA[3];
  unsigned eqCount;
  float A[3];
  unsigned tminbits;
  unsigned eqIdx[EQCAP];    // packed (low8<<24)|idx for 24-bit-prefix matches
  float tp1[NPATCH];
  float tp2[NPATCH];
};

// ---------- cooperative radix-select resolve (256 threads; fence-free) ----------
__device__ __forceinline__ void resolve_level(const unsigned* __restrict__ h,
                                              unsigned k_in, int desc,
                                              unsigned* lds,
                                              unsigned& chosen, unsigned& k_out) {
  int t = threadIdx.x;
  unsigned c = h[desc ? (255 - t) : t];
  lds[t] = c;
  __syncthreads();
  for (int s = 1; s < 256; s <<= 1) {           // Hillis-Steele inclusive scan
    unsigned add = (t >= s) ? lds[t - s] : 0u;
    __syncthreads();
    lds[t] += add;
    __syncthreads();
  }
  unsigned incl = lds[t];
  unsigned excl = incl - c;
  if (incl >= k_in && excl < k_in) { lds[256] = (unsigned)t; lds[257] = k_in - excl; }
  __syncthreads();
  unsigned tt = lds[256];
  k_out = lds[257];
  chosen = desc ? (255u - tt) : tt;
  __syncthreads();
}

// ---------- 1: init state + channel-min + horizontal 55-min (one row per block) ----------
__global__ __launch_bounds__(512) void k_rowmin(const float* __restrict__ img,
                                                float* __restrict__ rowmin, State* st) {
  __shared__ float l[534];
  int y = blockIdx.x, t = threadIdx.x;
  for (int i = t; i < 534; i += 512) {
    int col = i - 27;
    float v = 1.0f;                              // pad (constant_values=1.0)
    if ((unsigned)col < (unsigned)W) {
      int q = y * W + col;
      v = fminf(fminf(img[q], img[HW + q]), img[2 * HW + q]);
    }
    l[i] = v;
  }
  if (y == 0 && t < 256) {
    for (int i = 0; i < 3; ++i) st->histA[i][t] = 0u;
    if (t == 0) { st->sumA[0] = 0.f; st->sumA[1] = 0.f; st->sumA[2] = 0.f; st->eqCount = 0u; }
  }
  __syncthreads();
  if (t < W) {
    float m = l[t];
    for (int d = 1; d < 55; ++d) m = fminf(m, l[t + d]);
    rowmin[y * W + t] = m;
  }
}

// ---------- 2: vertical 8-row chunk mins (60 chunks x 480 cols) ----------
__global__ __launch_bounds__(256) void k_vchunk(const float* __restrict__ rowmin,
                                                float* __restrict__ cmin) {
  int p = blockIdx.x * 256 + threadIdx.x;
  if (p >= 60 * W) return;
  int c = p / W, x = p - c * W;
  float m = INFINITY;
  for (int r = 0; r < 8; ++r) m = fminf(m, rowmin[(c * 8 + r) * W + x]);
  cmin[p] = m;
}

// ---------- 3: vertical 55-min via chunks + edges, fused hist level-0 ----------
__global__ __launch_bounds__(256) void k_minV2(const float* __restrict__ rowmin,
                                               const float* __restrict__ cmin,
                                               float* __restrict__ dc, State* st) {
  __shared__ unsigned lh[256];
  int t = threadIdx.x;
  lh[t] = 0u;
  __syncthreads();
  int p = blockIdx.x * 256 + t;
  int y = p / W, x = p - y * W;
  int lo = y - 27, hi = y + 27;
  float m = (lo < 0 || hi >= HT) ? 1.0f : INFINITY;
  int lo2 = max(lo, 0), hi2 = min(hi, HT - 1);
  int cs = (lo2 + 7) >> 3, ce = ((hi2 + 1) >> 3) - 1;
  for (int c = cs; c <= ce; ++c) m = fminf(m, cmin[c * W + x]);
  for (int yy = lo2; yy < (cs << 3); ++yy) m = fminf(m, rowmin[yy * W + x]);
  for (int yy = (ce + 1) << 3; yy <= hi2; ++yy) m = fminf(m, rowmin[yy * W + x]);
  dc[p] = m;
  atomicAdd(&lh[__float_as_uint(m) >> 24], 1u);
  __syncthreads();
  unsigned c = lh[t];
  if (c) atomicAdd(&st->histA[0][t], c);
}

// ---------- 4,5: radix hist pass, resolves prior levels per block (fence-free) ----------
__global__ __launch_bounds__(256) void k_histL(const float* __restrict__ dc,
                                               State* st, int level) {
  __shared__ unsigned lds[258];
  int t = threadIdx.x;
  unsigned prefix = 0u, k = 230u;
  for (int j = 0; j < level; ++j) {
    unsigned ch, kn;
    resolve_level(st->histA[j], k, 1, lds, ch, kn);
    prefix |= ch << (24 - 8 * j);
    k = kn;
  }
  lds[t] = 0u;
  __syncthreads();
  int p = blockIdx.x * 256 + t;
  unsigned bits = __float_as_uint(dc[p]);
  unsigned mask = 0xFFFFFFFFu << (32 - 8 * level);
  if ((bits & mask) == prefix)
    atomicAdd(&lds[(bits >> (24 - 8 * level)) & 0xFFu], 1u);
  __syncthreads();
  unsigned c = lds[t];
  if (c) atomicAdd(&st->histA[level][t], c);
}

// ---------- 6: gather on 24-bit prefix (3 resolves), pack (low8|idx) ----------
__global__ __launch_bounds__(256) void k_gather24(const float* __restrict__ dc,
                                                  const float* __restrict__ img, State* st) {
  __shared__ unsigned lds[258];
  int t = threadIdx.x;
  unsigned prefix = 0u, k = 230u;
  for (int j = 0; j < 3; ++j) {
    unsigned ch, kn;
    resolve_level(st->histA[j], k, 1, lds, ch, kn);
    prefix |= ch << (24 - 8 * j);
    k = kn;
  }
  if (blockIdx.x == 0 && t == 0) { st->slotP2 = prefix; st->slotK2 = k; }
  int p = blockIdx.x * 256 + t;
  unsigned bits = __float_as_uint(dc[p]);
  unsigned top24 = bits & 0xFFFFFF00u;
  if (top24 > prefix) {
    atomicAdd(&st->sumA[0], img[p]);
    atomicAdd(&st->sumA[1], img[HW + p]);
    atomicAdd(&st->sumA[2], img[2 * HW + p]);
  } else if (top24 == prefix) {
    unsigned pos = atomicAdd(&st->eqCount, 1u);
    if (pos < (unsigned)EQCAP) st->eqIdx[pos] = ((bits & 0xFFu) << 24) | (unsigned)p;
  }
}

// ---------- 7: 1-block finalize: low-byte resolve + top_k tie-break + A ----------
__global__ __launch_bounds__(256) void k_finalize24(const float* __restrict__ img, State* st) {
  __shared__ unsigned sPk[EQCAP];
  __shared__ unsigned lh[256];
  __shared__ unsigned lds[258];
  __shared__ float ssum[3];
  int t = threadIdx.x;
  unsigned k24 = st->slotK2;
  unsigned ne = st->eqCount; if (ne > (unsigned)EQCAP) ne = EQCAP;
  for (int i = t; i < (int)ne; i += 256) sPk[i] = st->eqIdx[i];
  if (t < 3) ssum[t] = 0.f;
  lh[t] = 0u;
  __syncthreads();
  for (int i = t; i < (int)ne; i += 256) atomicAdd(&lh[sPk[i] >> 24], 1u);
  __syncthreads();
  unsigned lb, keq;
  resolve_level(lh, k24, 1, lds, lb, keq);   // low byte of threshold; keq ties needed
  float a0 = 0.f, a1 = 0.f, a2 = 0.f;
  for (int i = t; i < (int)ne; i += 256) {
    unsigned v = sPk[i];
    if ((v >> 24) > lb) {
      unsigned q = v & 0x3FFFFu;
      a0 += img[q]; a1 += img[HW + q]; a2 += img[2 * HW + q];
    }
  }
  // lax.top_k tie-break = lower index first: keq smallest idx among low==lb
  unsigned pfi = 0u, kk = keq;
  for (int lev = 0; lev < 3; ++lev) {
    int s = 16 - 8 * lev;
    __syncthreads();
    lh[t] = 0u;
    __syncthreads();
    for (int i = t; i < (int)ne; i += 256) {
      unsigned v = sPk[i];
      if ((v >> 24) == lb) {
        unsigned idx = v & 0x3FFFFu;
        if ((idx >> (s + 8)) == (pfi >> (s + 8)))
          atomicAdd(&lh[(idx >> s) & 0xFFu], 1u);
      }
    }
    __syncthreads();
    unsigned ch, kn;
    resolve_level(lh, kk, 0, lds, ch, kn);
    pfi |= ch << s;
    kk = kn;
  }
  for (int i = t; i < (int)ne; i += 256) {
    unsigned v = sPk[i];
    if ((v >> 24) == lb) {
      unsigned q = v & 0x3FFFFu;
      if (q <= pfi) { a0 += img[q]; a1 += img[HW + q]; a2 += img[2 * HW + q]; }
    }
  }
  atomicAdd(&ssum[0], a0); atomicAdd(&ssum[1], a1); atomicAdd(&ssum[2], a2);
  __syncthreads();
  if (t == 0) {
    st->A[0] = (st->sumA[0] + ssum[0]) / 230.0f;
    st->A[1] = (st->sumA[1] + ssum[1]) / 230.0f;
    st->A[2] = (st->sumA[2] + ssum[2]) / 230.0f;
  }
}

// ---------- 8: row kernel: SV, I + fused bccr 15-tap H-maxpool (LDS) ----------
__global__ __launch_bounds__(512) void k_elem_row(const float* __restrict__ img,
                                                  const State* __restrict__ st,
                                                  float2* __restrict__ SV,
                                                  float* __restrict__ Io,
                                                  float* __restrict__ mh) {
  __shared__ float Tl[494];
  int y = blockIdx.x, t = threadIdx.x;
  if (t < 7) Tl[t] = 0.0f;                        // left pad 0
  if (t >= 480 && t < 487) Tl[t + 7] = 0.0f;      // right pad 0
  if (t < W) {
    int p = y * W + t;
    float A0 = st->A[0], A1 = st->A[1], A2 = st->A[2];
    float r = img[p], g = img[HW + p], bl = img[2 * HW + p];
    float nr = r / A0, ng = g / A1, nb = bl / A2;
    float mx = fmaxf(fmaxf(nr, ng), nb);
    float mn = fminf(fminf(nr, ng), nb);
    float d = mx + 1e-8f;
    SV[p] = make_float2(1.0f / d, 1.0f - mn / d);  // x = X (V1), y = Y (S)
    Io[p] = ((r + g) + bl) / 3.0f;
    const float c20 = (float)(20.0 / 255.0);
    const float c300 = (float)(300.0 / 255.0);
    float t0 = fmaxf((A0 - r) / (A0 - c20), (A0 - r) / (A0 - c300));
    float t1 = fmaxf((A1 - g) / (A1 - c20), (A1 - g) / (A1 - c300));
    float t2 = fmaxf((A2 - bl) / (A2 - c20), (A2 - bl) / (A2 - c300));
    Tl[7 + t] = fmaxf(fmaxf(t0, t1), t2);
  }
  __syncthreads();
  if (t < W) {
    float m = Tl[t];
    for (int d = 1; d < 15; ++d) m = fmaxf(m, Tl[t + d]);
    mh[y * W + t] = m;
  }
}

// ---------- wave reductions ----------
__device__ __forceinline__ float wred_sum(float v) { for (int m = 32; m; m >>= 1) v += __shfl_xor(v, m, 64); return v; }
__device__ __forceinline__ float wred_max(float v) { for (int m = 32; m; m >>= 1) v = fmaxf(v, __shfl_xor(v, m, 64)); return v; }
__device__ __forceinline__ float wred_min(float v) { for (int m = 32; m; m >>= 1) v = fminf(v, __shfl_xor(v, m, 64)); return v; }

// ---------- 9: both patch grids (sign/magnitude slope test) ----------
__global__ __launch_bounds__(256) void k_mega1(const float2* __restrict__ SV, State* st) {
  __shared__ float2 XY[PP];
  __shared__ float part[4][8];
  int b = blockIdx.x;
  int t = threadIdx.x;
  int mode = b >> 10;              // 0: t1 grid, 1: shifted t2 grid
  int pid = b & 1023;
  int ph = pid >> 5, pw = pid & 31;
  if (t < PP) {
    int r = t / 15, c = t - (t / 15) * 15;
    int y, x;
    if (mode == 0) { y = ph * 15 + r; x = pw * 15 + c; }
    else {
      y = ph * 15 + r + 4; y = (y < 7) ? 7 : ((y > 479) ? 479 : y);
      x = pw * 15 + c + 4; x = (x < 7) ? 7 : ((x > 479) ? 479 : x);
    }
    XY[t] = SV[y * W + x];
  }
  __syncthreads();
  float xi = 0.f, yi = 0.f;
  int cnt = 0;
  if (t < PP) {
    xi = XY[t].x; yi = XY[t].y;
    // slope = dY/(dX+1e-8) in (-1,0)  <=>  dY*D < 0  AND  |dY| < |D|
    for (int j = 0; j < PP; ++j) {
      float2 o = XY[j];
      float dY = yi - o.y;
      float D = (xi - o.x) + 1e-8f;
      cnt += ((dY * D < 0.0f) && (fabsf(dY) < fabsf(D))) ? 1 : 0;
    }
  }
  float pmf = (t < PP && cnt >= 113) ? 1.0f : 0.0f;   // scount >= 112.5
  float xm = xi * pmf, ym = yi * pmf;
  float v0 = wred_sum(pmf);
  float v1 = wred_sum(xm);
  float v2 = wred_sum(ym);
  float v3 = wred_sum(xm * ym);
  float v4 = wred_sum(xm * xm);
  float v5 = wred_max((t < PP) ? xm : -INFINITY);
  float v6 = wred_min((t < PP) ? (xi + 1e8f * (1.0f - pmf)) : INFINITY);
  int wid = t >> 6, lane = t & 63;
  if (lane == 0) {
    part[wid][0] = v0; part[wid][1] = v1; part[wid][2] = v2; part[wid][3] = v3;
    part[wid][4] = v4; part[wid][5] = v5; part[wid][6] = v6;
  }
  __syncthreads();
  if (t == 0) {
    float pcount = 0.f, sx = 0.f, sy = 0.f, sxy = 0.f, sxx = 0.f;
    float mxX = -INFINITY, mnX = INFINITY;
    for (int w2 = 0; w2 < 4; ++w2) {
      pcount += part[w2][0]; sx += part[w2][1]; sy += part[w2][2];
      sxy += part[w2][3]; sxx += part[w2][4];
      mxX = fmaxf(mxX, part[w2][5]); mnX = fminf(mnX, part[w2][6]);
    }
    float den = pcount + 1e-5f;
    float mxv = sx / den, myv = sy / den;
    float kk = (sxy - pcount * mxv * myv) / (sxx - pcount * (mxv * mxv) + 1e-5f);
    float bb = myv - kk * mxv;
    float tt = 1.0f + kk / (bb + 1e-8f);
    float len = sqrtf(1.0f + kk * kk) * (mxX - mnX);
    bool m = (pcount > 10.0f) && (len > 0.1f) && (kk > -1.0f) && (kk < 0.0f)
             && (tt > 0.01f) && (tt < 0.99f);
    float res = tt * (m ? 1.0f : 0.0f);   // keep JAX NaN*0 semantics
    if (mode == 0) st->tp1[pid] = res; else st->tp2[pid] = res;
  }
}

// ---------- 10: 2-row bccr V-maxpool+clip (blocks 0..449) | analytic percentile (450) ----------
__global__ __launch_bounds__(256) void k_maxV_pct(const float* __restrict__ mh,
                                                  float* __restrict__ tb, State* st) {
  __shared__ unsigned lh[256];
  __shared__ unsigned lds[258];
  __shared__ float tp1s[NPATCH], tp2s[NPATCH];
  int b = blockIdx.x;
  int t = threadIdx.x;
  if (b < 450) {
    int p = b * 256 + t;          // [0, HW/2)
    int x = p % W, yp = p / W;
    int y0 = 2 * yp;
    float m0 = -INFINITY, m1 = -INFINITY;
    for (int d = 0; d < 16; ++d) {
      int yy = y0 - 7 + d;
      float v = ((unsigned)yy < (unsigned)HT) ? mh[yy * W + x] : 0.0f;
      if (d < 15) m0 = fmaxf(m0, v);
      if (d > 0)  m1 = fmaxf(m1, v);
    }
    tb[y0 * W + x]       = fminf(fmaxf(m0, 0.05f), 1.0f);
    tb[(y0 + 1) * W + x] = fminf(fmaxf(m1, 0.05f), 1.0f);
    return;
  }
  // percentile: t_slp piecewise constant over <=4096 (value, area) regions
  for (int i = t; i < NPATCH; i += 256) { tp1s[i] = st->tp1[i]; tp2s[i] = st->tp2[i]; }
  __syncthreads();
  unsigned prefix = 0u, k = 11521u;   // 1-based rank of sorted[11520]
  for (int level = 0; level < 4; ++level) {
    lh[t] = 0u;
    __syncthreads();
    unsigned mask = (level == 0) ? 0u : (0xFFFFFFFFu << (32 - 8 * level));
    int shift = 24 - 8 * level;
    for (int i = t; i < NPATCH; i += 256) {
      int ph = i >> 5, pw = i & 31;
      float a = tp1s[i];
      int rcnt[2], ridx[2], ccnt[2], cidx[2];
      if (ph == 0) { rcnt[0] = 7; ridx[0] = -1; rcnt[1] = 8; ridx[1] = 0; }
      else         { rcnt[0] = 4; ridx[0] = ph - 1; rcnt[1] = 11; ridx[1] = ph; }
      if (pw == 0) { ccnt[0] = 7; cidx[0] = -1; ccnt[1] = 8; cidx[1] = 0; }
      else         { ccnt[0] = 4; cidx[0] = pw - 1; ccnt[1] = 11; cidx[1] = pw; }
      for (int ri = 0; ri < 2; ++ri)
        for (int ci = 0; ci < 2; ++ci) {
          unsigned area = (unsigned)(rcnt[ri] * ccnt[ci]);
          float bb = 0.0f;
          if (ridx[ri] >= 0 && cidx[ci] >= 0) bb = tp2s[ridx[ri] * 32 + cidx[ci]];
          float r;
          if (a != 0.0f && bb != 0.0f) r = (a + bb) / 2.0f;
          else r = (a != 0.0f) ? a : bb;
          float u = (r > 0.0f) ? r : 10.0f;            // where(t>0,t,10); NaN->10
          unsigned bits = __float_as_uint(u);
          if ((bits & mask) == prefix)
            atomicAdd(&lh[(bits >> shift) & 0xFFu], area);
        }
    }
    __syncthreads();
    unsigned ch, kn;
    resolve_level(lh, k, 0, lds, ch, kn);
    prefix |= ch << shift;
    k = kn;
  }
  if (t == 0) st->tminbits = prefix;
}

// ---------- 11: gf pass-1 horizontal (one row/block), fused t_fusion, float4 out ----------
__global__ __launch_bounds__(512) void k_gf1h(const float* __restrict__ I,
                                              const float* __restrict__ tb,
                                              const State* __restrict__ st,
                                              float4* __restrict__ box4) {
  __shared__ float tp1s[NPATCH], tp2s[NPATCH];
  __shared__ float Pl[540], Il[540];
  int y = blockIdx.x, t = threadIdx.x;
  for (int i = t; i < NPATCH; i += 512) { tp1s[i] = st->tp1[i]; tp2s[i] = st->tp2[i]; }
  __syncthreads();
  float tmin = __uint_as_float(st->tminbits);
  int c1row = (y / 15) * 32;
  bool c2ok = (y >= 7);
  int c2row = c2ok ? ((y - 4) / 15) * 32 : 0;
  for (int i = t; i < 540; i += 512) {
    int col = i - 30;
    float pv = 0.0f, iv = 0.0f;
    if ((unsigned)col < (unsigned)W) {
      int q = y * W + col;
      float a = tp1s[c1row + col / 15];
      float bb = 0.0f;
      if (c2ok && col >= 7) bb = tp2s[c2row + (col - 4) / 15];
      float r;
      if (a != 0.0f && bb != 0.0f) r = (a + bb) / 2.0f;   // NaN != 0 true, as in JAX
      else r = (a != 0.0f) ? a : bb;
      float v = (r > 0.0f) ? r : tb[q];                   // NaN -> tb
      v = (v < tmin) ? tmin : v;
      v = (v > 1.0f) ? 1.0f : v;
      pv = v; iv = I[q];
    }
    Pl[i] = pv; Il[i] = iv;
  }
  __syncthreads();
  if (t < W) {
    float sI = 0.f, sP = 0.f, sIp = 0.f, sII = 0.f;
    for (int d = 0; d < 61; ++d) {
      float iv = Il[t + d], pv = Pl[t + d];
      sI += iv; sP += pv; sIp += iv * pv; sII += iv * iv;
    }
    box4[y * W + t] = make_float4(sI, sP, sIp, sII);
  }
}

// ---------- 12: gf pass-1 vertical, 2 rows/thread ----------
__global__ __launch_bounds__(256) void k_gf1v(const float4* __restrict__ box4,
                                              float2* __restrict__ ab) {
  int p = blockIdx.x * 256 + threadIdx.x;   // [0, HW/2)
  int x = p % W, yp = p / W;
  int y0 = 2 * yp, y1 = y0 + 1;
  float sI = 0.f, sP = 0.f, sIp = 0.f, sII = 0.f;
  int lo = max(y0 - 30, 0), hi = min(y0 + 30, HT - 1);
  for (int yy = lo; yy <= hi; ++yy) {
    float4 v = box4[yy * W + x];
    sI += v.x; sP += v.y; sIp += v.z; sII += v.w;
  }
  int nx = min(x + 30, W - 1) - max(x - 30, 0) + 1;
  {
    float Nn = (float)((hi - lo + 1) * nx);
    float mI = sI / Nn, mP = sP / Nn, mIp = sIp / Nn, mII = sII / Nn;
    float cov = mIp - mI * mP;
    float var = mII - mI * mI;
    float av = cov / (var + 1e-3f);
    ab[y0 * W + x] = make_float2(av, mP - av * mI);
  }
  {
    int yr = y0 - 30, ya = y0 + 31;
    if (yr >= 0)  { float4 v = box4[yr * W + x]; sI -= v.x; sP -= v.y; sIp -= v.z; sII -= v.w; }
    if (ya < HT)  { float4 v = box4[ya * W + x]; sI += v.x; sP += v.y; sIp += v.z; sII += v.w; }
    int lo1 = max(y1 - 30, 0), hi1 = min(y1 + 30, HT - 1);
    float Nn = (float)((hi1 - lo1 + 1) * nx);
    float mI = sI / Nn, mP = sP / Nn, mIp = sIp / Nn, mII = sII / Nn;
    float cov = mIp - mI * mP;
    float var = mII - mI * mI;
    float av = cov / (var + 1e-3f);
    ab[y1 * W + x] = make_float2(av, mP - av * mI);
  }
}

// ---------- 13: gf pass-2 horizontal (one row/block), float2 in/out ----------
__global__ __launch_bounds__(512) void k_gf2h(const float2* __restrict__ ab,
                                              float2* __restrict__ hab) {
  __shared__ float2 l[540];
  int y = blockIdx.x, t = threadIdx.x;
  for (int i = t; i < 540; i += 512) {
    int col = i - 30;
    float2 v = make_float2(0.f, 0.f);
    if ((unsigned)col < (unsigned)W) v = ab[y * W + col];
    l[i] = v;
  }
  __syncthreads();
  if (t < W) {
    float sa = 0.f, sb = 0.f;
    for (int d = 0; d < 61; ++d) { float2 v = l[t + d]; sa += v.x; sb += v.y; }
    hab[y * W + t] = make_float2(sa, sb);
  }
}

// ---------- 14: gf pass-2 vertical + restore epilogue, 2 rows/thread ----------
__global__ __launch_bounds__(256) void k_gf2vfin(const float2* __restrict__ hab,
                                                 const float* __restrict__ I,
                                                 const float* __restrict__ img,
                                                 const State* __restrict__ st,
                                                 float* __restrict__ out) {
  int p = blockIdx.x * 256 + threadIdx.x;   // [0, HW/2)
  int x = p % W, yp = p / W;
  int y0 = 2 * yp, y1 = y0 + 1;
  float A0 = st->A[0], A1 = st->A[1], A2 = st->A[2];
  float sa = 0.f, sb = 0.f;
  int lo = max(y0 - 30, 0), hi = min(y0 + 30, HT - 1);
  for (int yy = lo; yy <= hi; ++yy) { float2 v = hab[yy * W + x]; sa += v.x; sb += v.y; }
  int nx = min(x + 30, W - 1) - max(x - 30, 0) + 1;
  {
    float Nn = (float)((hi - lo + 1) * nx);
    int q = y0 * W + x;
    float tref = (sa / Nn) * I[q] + (sb / Nn);
    out[q]          = (img[q]          - A0) / tref + A0;
    out[HW + q]     = (img[HW + q]     - A1) / tref + A1;
    out[2 * HW + q] = (img[2 * HW + q] - A2) / tref + A2;
  }
  {
    int yr = y0 - 30, ya = y0 + 31;
    if (yr >= 0) { float2 v = hab[yr * W + x]; sa -= v.x; sb -= v.y; }
    if (ya < HT) { float2 v = hab[ya * W + x]; sa += v.x; sb += v.y; }
    int lo1 = max(y1 - 30, 0), hi1 = min(y1 + 30, HT - 1);
    float Nn = (float)((hi1 - lo1 + 1) * nx);
    int q = y1 * W + x;
    float tref = (sa / Nn) * I[q] + (sb / Nn);
    out[q]          = (img[q]          - A0) / tref + A0;
    out[HW + q]     = (img[HW + q]     - A1) / tref + A1;
    out[2 * HW + q] = (img[2 * HW + q] - A2) / tref + A2;
  }
}

// ---------- launch: 14 dispatches ----------
extern "C" void kernel_launch(void* const* d_in, const int* in_sizes, int n_in,
                              void* d_out, int out_size, void* d_ws, size_t ws_size,
                              hipStream_t stream) {
  (void)in_sizes; (void)n_in; (void)out_size; (void)ws_size;
  const float* img = (const float*)d_in[0];
  float* out = (float*)d_out;
  State* st = (State*)d_ws;
  float* sb = (float*)((char*)d_ws + 65536);
  float* bufA  = sb;                          // dc -> tb
  float* bufRM = sb + HW;                     // rowmin
  float* bufI  = sb + 2 * HW;                 // I
  float2* SV   = (float2*)(sb + 3 * HW);      // [3HW,5HW)
  float* cmin  = sb + 5 * HW;                 // 28800 floats
  float* mh    = sb + 6 * HW;                 // [6HW,7HW)
  float4* box4 = (float4*)(sb + 3 * HW);      // [3HW,7HW)  (SV/cmin/mh dead by then)
  float2* ab   = (float2*)(sb + 7 * HW);      // [7HW,9HW)
  float2* hab  = (float2*)(sb + 3 * HW);      // [3HW,5HW)  (box4 dead by then)

  dim3 b256(256), b512(512);
  dim3 ge(GE), rows(HT), half(450);

  k_rowmin<<<rows, b512, 0, stream>>>(img, bufRM, st);
  k_vchunk<<<dim3(113), b256, 0, stream>>>(bufRM, cmin);
  k_minV2<<<ge, b256, 0, stream>>>(bufRM, cmin, bufA, st);
  k_histL<<<ge, b256, 0, stream>>>(bufA, st, 1);
  k_histL<<<ge, b256, 0, stream>>>(bufA, st, 2);
  k_gather24<<<ge, b256, 0, stream>>>(bufA, img, st);
  k_finalize24<<<dim3(1), b256, 0, stream>>>(img, st);
  k_elem_row<<<rows, b512, 0, stream>>>(img, st, SV, bufI, mh);
  k_mega1<<<dim3(2048), b256, 0, stream>>>(SV, st);
  k_maxV_pct<<<dim3(451), b256, 0, stream>>>(mh, bufA, st);
  k_gf1h<<<rows, b512, 0, stream>>>(bufI, bufA, st, box4);
  k_gf1v<<<half, b256, 0, stream>>>(box4, ab);
  k_gf2h<<<rows, b512, 0, stream>>>(ab, hab);
  k_gf2vfin<<<half, b256, 0, stream>>>(hab, bufI, img, st, out);
}